// Round 4
// baseline (1660.482 us; speedup 1.0000x reference)
//
#include <hip/hip_runtime.h>
#include <hip/hip_bf16.h>
#include <math.h>

typedef __hip_bfloat16 bf16;

#define N_NODES_C 100000
#define N_EDGES_C 600000
#define N_CENTER_C 512
#define N_NONMOL_C 20000
#define N_REL_C 50
#define D_C 128
#define N_MOTIF_C 85

// element offsets into d_out (dtype-independent)
#define EO_EDGE  0L
#define EO_MOTIF 30000000L
#define EO_NODEC 30043520L
#define EO_BIN   30343520L

__device__ __forceinline__ float b2f(bf16 v) { return __bfloat162float(v); }
__device__ __forceinline__ void stf(bf16* p, float v) { *p = __float2bfloat16(v); }
__device__ __forceinline__ void stf(float* p, float v) { *p = v; }

// runtime-dtype load of a "reference float tensor" element
__device__ __forceinline__ float ldf(const void* p, size_t i, int isbf) {
    return isbf ? __bfloat162float(((const bf16*)p)[i]) : ((const float*)p)[i];
}
// runtime-dtype store into d_out (element index)
__device__ __forceinline__ void stout(void* p, size_t i, int isbf, float v) {
    if (isbf) ((bf16*)p)[i] = __float2bfloat16(v);
    else      ((float*)p)[i] = v;
}

// ---- dtype probe: bf16 data is all finite & |x|<~6; fp32-read-as-bf16 is wild ----
__global__ void probe_kernel(const void* __restrict__ table, int* __restrict__ flag) {
    __shared__ int bad[256];
    int t = threadIdx.x;
    const bf16* p = (const bf16*)table;
    int cnt = 0;
    for (int i = 0; i < 64; i++) {
        float v = __bfloat162float(p[t * 64 + i]);
        if (!isfinite(v) || fabsf(v) > 1000.0f) cnt++;
    }
    bad[t] = cnt;
    __syncthreads();
    for (int s = 128; s > 0; s >>= 1) {
        if (t < s) bad[t] += bad[t + s];
        __syncthreads();
    }
    if (t == 0) *flag = (bad[0] == 0) ? 1 : 0;   // 1 = bf16, 0 = fp32
}

// out[row] = relu(l2norm(table[ids[row]]) @ W + b)   (ids==nullptr -> identity)
template <typename OUT>
__global__ void embed_lin_kernel(const int* __restrict__ flag,
                                 const int* __restrict__ ids,
                                 const void* __restrict__ table,
                                 const void* __restrict__ W,
                                 const void* __restrict__ bias,
                                 OUT* __restrict__ out) {
    int isbf = *flag;
    int row = blockIdx.x;
    int t = threadIdx.x;
    int id = ids ? ids[row] : row;
    float v = ldf(table, (size_t)id * D_C + t, isbf);

    __shared__ float sv[D_C];
    __shared__ float red[D_C];
    red[t] = v * v;
    __syncthreads();
    for (int s = 64; s > 0; s >>= 1) {
        if (t < s) red[t] += red[t + s];
        __syncthreads();
    }
    float nrm = fmaxf(sqrtf(red[0]), 1e-12f);
    sv[t] = v / nrm;
    __syncthreads();

    float acc = ldf(bias, t, isbf);
    if (isbf) {
        const bf16* Wp = (const bf16*)W;
#pragma unroll 8
        for (int k = 0; k < D_C; k++) acc = fmaf(sv[k], b2f(Wp[k * D_C + t]), acc);
    } else {
        const float* Wp = (const float*)W;
#pragma unroll 8
        for (int k = 0; k < D_C; k++) acc = fmaf(sv[k], Wp[k * D_C + t], acc);
    }
    stf(&out[(size_t)row * D_C + t], fmaxf(acc, 0.0f));
}

// agg[dst] += relu(x[src] + etab[rel])  (one thread per (edge, feature))
__global__ void scatter_kernel(const bf16* __restrict__ x,
                               const int* __restrict__ ei,
                               const int* __restrict__ rel,
                               const float* __restrict__ etab,
                               float* __restrict__ agg) {
    long idx = (long)blockIdx.x * blockDim.x + threadIdx.x;
    if (idx >= (long)N_EDGES_C * D_C) return;
    int e = (int)(idx >> 7);
    int t = (int)(idx & (D_C - 1));
    int src = ei[e];
    int dst = ei[N_EDGES_C + e];
    int r = rel[e];
    float m = b2f(x[(size_t)src * D_C + t]) + etab[r * D_C + t];
    m = fmaxf(m, 0.0f);
    atomicAdd(&agg[(size_t)dst * D_C + t], m);
}

// out[row] = maybe_relu((x[row]+agg[row]) @ W + b)
template <bool RELU>
__global__ void gine_update_kernel(const int* __restrict__ flag,
                                   const bf16* __restrict__ x,
                                   const float* __restrict__ agg,
                                   const void* __restrict__ W,
                                   const void* __restrict__ bias,
                                   bf16* __restrict__ out) {
    int isbf = *flag;
    int row = blockIdx.x;
    int t = threadIdx.x;
    __shared__ float sv[D_C];
    sv[t] = b2f(x[(size_t)row * D_C + t]) + agg[(size_t)row * D_C + t];
    __syncthreads();
    float acc = ldf(bias, t, isbf);
    if (isbf) {
        const bf16* Wp = (const bf16*)W;
#pragma unroll 8
        for (int k = 0; k < D_C; k++) acc = fmaf(sv[k], b2f(Wp[k * D_C + t]), acc);
    } else {
        const float* Wp = (const float*)W;
#pragma unroll 8
        for (int k = 0; k < D_C; k++) acc = fmaf(sv[k], Wp[k * D_C + t], acc);
    }
    if (RELU) acc = fmaxf(acc, 0.0f);
    out[(size_t)row * D_C + t] = __float2bfloat16(acc);
}

// P[row] = x[row] @ edge_W[0:128, :], Q[row] = x[row] @ edge_W[128:256, :]
__global__ void pq_kernel(const int* __restrict__ flag,
                          const bf16* __restrict__ x,
                          const void* __restrict__ eW,
                          bf16* __restrict__ P,
                          bf16* __restrict__ Q) {
    int isbf = *flag;
    int row = blockIdx.x;
    int t = threadIdx.x;
    __shared__ float sv[D_C];
    sv[t] = b2f(x[(size_t)row * D_C + t]);
    __syncthreads();
    int half = (t >= 64);
    int j = half ? t - 64 : t;
    if (j < N_REL_C) {
        int base = half ? D_C : 0;
        float acc = 0.0f;
        if (isbf) {
            const bf16* Wp = (const bf16*)eW;
#pragma unroll 8
            for (int k = 0; k < D_C; k++) acc = fmaf(sv[k], b2f(Wp[(base + k) * N_REL_C + j]), acc);
        } else {
            const float* Wp = (const float*)eW;
#pragma unroll 8
            for (int k = 0; k < D_C; k++) acc = fmaf(sv[k], Wp[(base + k) * N_REL_C + j], acc);
        }
        bf16* dstp = half ? Q : P;
        dstp[(size_t)row * N_REL_C + j] = __float2bfloat16(acc);
    }
}

// out[e*50+j] = P[src[e]][j] + Q[dst[e]][j] + edge_b[j]
__global__ void edge_out_kernel(const int* __restrict__ flag,
                                const int* __restrict__ ei,
                                const bf16* __restrict__ P,
                                const bf16* __restrict__ Q,
                                const void* __restrict__ eb,
                                void* __restrict__ out) {
    int isbf = *flag;
    long g = (long)blockIdx.x * blockDim.x + threadIdx.x;
    if (g >= (long)N_EDGES_C * N_REL_C) return;
    int e = (int)(g / N_REL_C);
    int j = (int)(g - (long)e * N_REL_C);
    int src = ei[e];
    int dst = ei[N_EDGES_C + e];
    float v = b2f(P[(size_t)src * N_REL_C + j]) + b2f(Q[(size_t)dst * N_REL_C + j]) + ldf(eb, j, isbf);
    stout(out, EO_EDGE + g, isbf, v);
}

__global__ void motif_kernel(const int* __restrict__ flag,
                             const int* __restrict__ cidx,
                             const bf16* __restrict__ x,
                             const void* __restrict__ W,
                             const void* __restrict__ bias,
                             void* __restrict__ out) {
    int isbf = *flag;
    int row = blockIdx.x;
    int t = threadIdx.x;
    __shared__ float sv[D_C];
    int id = cidx[row];
    sv[t] = b2f(x[(size_t)id * D_C + t]);
    __syncthreads();
    if (t < N_MOTIF_C) {
        float acc = ldf(bias, t, isbf);
        if (isbf) {
            const bf16* Wp = (const bf16*)W;
#pragma unroll 8
            for (int k = 0; k < D_C; k++) acc = fmaf(sv[k], b2f(Wp[k * N_MOTIF_C + t]), acc);
        } else {
            const float* Wp = (const float*)W;
#pragma unroll 8
            for (int k = 0; k < D_C; k++) acc = fmaf(sv[k], Wp[k * N_MOTIF_C + t], acc);
        }
        stout(out, EO_MOTIF + (size_t)row * N_MOTIF_C + t, isbf, acc);
    }
}

__global__ void nodec_kernel(const int* __restrict__ flag,
                             const int* __restrict__ nidx,
                             const bf16* __restrict__ x,
                             const void* __restrict__ W,
                             const void* __restrict__ bias,
                             void* __restrict__ out) {
    int isbf = *flag;
    int g = blockIdx.x * blockDim.x + threadIdx.x;
    if (g >= N_NONMOL_C * 15) return;
    int row = g / 15;
    int j = g - row * 15;
    int id = nidx[row];
    float acc = ldf(bias, j, isbf);
    if (isbf) {
        const bf16* Wp = (const bf16*)W;
#pragma unroll 8
        for (int k = 0; k < D_C; k++) acc = fmaf(b2f(x[(size_t)id * D_C + k]), b2f(Wp[k * 15 + j]), acc);
    } else {
        const float* Wp = (const float*)W;
#pragma unroll 8
        for (int k = 0; k < D_C; k++) acc = fmaf(b2f(x[(size_t)id * D_C + k]), Wp[k * 15 + j], acc);
    }
    stout(out, EO_NODEC + g, isbf, acc);
}

// one wave (64 lanes) per node row: out[row] = x[row] @ bin_W + bin_b
__global__ void binary_kernel(const int* __restrict__ flag,
                              const bf16* __restrict__ x,
                              const void* __restrict__ W,
                              const void* __restrict__ bias,
                              void* __restrict__ out) {
    int isbf = *flag;
    int g = blockIdx.x * blockDim.x + threadIdx.x;
    int row = g >> 6;
    int lane = threadIdx.x & 63;
    if (row >= N_NODES_C) return;
    float a = b2f(x[(size_t)row * D_C + lane]) * ldf(W, lane, isbf) +
              b2f(x[(size_t)row * D_C + 64 + lane]) * ldf(W, 64 + lane, isbf);
#pragma unroll
    for (int off = 32; off > 0; off >>= 1) a += __shfl_down(a, off, 64);
    if (lane == 0) stout(out, EO_BIN + row, isbf, a + ldf(bias, 0, isbf));
}

extern "C" void kernel_launch(void* const* d_in, const int* in_sizes, int n_in,
                              void* d_out, int out_size, void* d_ws, size_t ws_size,
                              hipStream_t stream) {
    const int* node_ids = (const int*)d_in[0];
    const int* rel_ids  = (const int*)d_in[1];
    const int* center   = (const int*)d_in[2];
    const int* nonmol   = (const int*)d_in[3];
    const int* ei       = (const int*)d_in[4];
    const void* node_emb = d_in[5];
    const void* rel_emb  = d_in[6];
    const void* lin_W = d_in[7];
    const void* lin_b = d_in[8];
    const void* W1 = d_in[9];
    const void* b1 = d_in[10];
    const void* W2 = d_in[11];
    const void* b2 = d_in[12];
    const void* edge_W = d_in[13];
    const void* edge_b = d_in[14];
    const void* motif_W = d_in[15];
    const void* motif_b = d_in[16];
    const void* nodec_W = d_in[17];
    const void* nodec_b = d_in[18];
    const void* bin_W = d_in[19];
    const void* bin_b = d_in[20];

    // ---- ws layout (51.23 MB): X0, X1 bf16 node-feature buffers + ET + flag ----
    char* wsb = (char*)d_ws;
    bf16* X0 = (bf16*)wsb;                                    // x0, later x2
    bf16* X1 = (bf16*)(wsb + (size_t)N_NODES_C * D_C * 2);    // x1, later P/Q
    float* ET = (float*)(wsb + (size_t)2 * N_NODES_C * D_C * 2);        // [50,128] fp32
    int* FLAG = (int*)(wsb + (size_t)2 * N_NODES_C * D_C * 2 + N_REL_C * D_C * 4);
    bf16* X2 = X0;
    bf16* P  = X1;                               // [N,50] after x1 is dead
    bf16* Q  = X1 + (size_t)N_NODES_C * N_REL_C;

    // ---- AGG fp32 scratch lives in d_out bytes [0, 51.2MB) — dead before any
    // output element is written (outputs at elem>=30e6 are byte>=60MB in bf16
    // case / >=120MB in fp32 case; edge_out (elems 0..30e6) runs after gine2).
    float* AGG = (float*)d_out;
    const size_t agg_bytes = (size_t)N_NODES_C * D_C * sizeof(float);

    // dtype probe (writes FLAG; everything downstream reads it on-device)
    probe_kernel<<<1, 256, 0, stream>>>(node_emb, FLAG);

    // ET = relu(l2norm(rel_emb) @ lin_W + lin_b)   [50,128] fp32
    embed_lin_kernel<float><<<N_REL_C, D_C, 0, stream>>>(FLAG, nullptr, rel_emb, lin_W, lin_b, ET);
    // X0 = relu(l2norm(node_emb[node_ids]) @ lin_W + lin_b)  bf16
    embed_lin_kernel<bf16><<<N_NODES_C, D_C, 0, stream>>>(FLAG, node_ids, node_emb, lin_W, lin_b, X0);

    long sthreads = (long)N_EDGES_C * D_C;
    int sblocks = (int)((sthreads + 255) / 256);

    // GINE conv 1
    hipMemsetAsync(AGG, 0, agg_bytes, stream);
    scatter_kernel<<<sblocks, 256, 0, stream>>>(X0, ei, rel_ids, ET, AGG);
    gine_update_kernel<true><<<N_NODES_C, D_C, 0, stream>>>(FLAG, X0, AGG, W1, b1, X1);

    // GINE conv 2
    hipMemsetAsync(AGG, 0, agg_bytes, stream);
    scatter_kernel<<<sblocks, 256, 0, stream>>>(X1, ei, rel_ids, ET, AGG);
    gine_update_kernel<false><<<N_NODES_C, D_C, 0, stream>>>(FLAG, X1, AGG, W2, b2, X2);

    // edge head: P = x2 @ edge_W[:128], Q = x2 @ edge_W[128:]  (X1 slot is dead)
    pq_kernel<<<N_NODES_C, D_C, 0, stream>>>(FLAG, X2, edge_W, P, Q);
    long ethreads = (long)N_EDGES_C * N_REL_C;
    edge_out_kernel<<<(int)((ethreads + 255) / 256), 256, 0, stream>>>(FLAG, ei, P, Q, edge_b, d_out);

    // small heads (read X2 from ws; write final outputs)
    motif_kernel<<<N_CENTER_C, D_C, 0, stream>>>(FLAG, center, X2, motif_W, motif_b, d_out);
    nodec_kernel<<<(N_NONMOL_C * 15 + 255) / 256, 256, 0, stream>>>(FLAG, nonmol, X2, nodec_W, nodec_b, d_out);
    binary_kernel<<<(N_NODES_C * 64 + 255) / 256, 256, 0, stream>>>(FLAG, X2, bin_W, bin_b, d_out);
}

// Round 5
// 1052.601 us; speedup vs baseline: 1.5775x; 1.5775x over previous
//
#include <hip/hip_runtime.h>
#include <hip/hip_bf16.h>
#include <math.h>

typedef __hip_bfloat16 bf16;
typedef __attribute__((ext_vector_type(8))) short short8;
typedef __attribute__((ext_vector_type(4))) float float4v;

#define N_NODES_C 100000
#define N_EDGES_C 600000
#define N_CENTER_C 512
#define N_NONMOL_C 20000
#define N_REL_C 50
#define D_C 128
#define N_MOTIF_C 85

// element offsets into d_out (dtype-independent)
#define EO_EDGE  0L
#define EO_MOTIF 30000000L
#define EO_NODEC 30043520L
#define EO_BIN   30343520L

// byte offsets of scratch inside d_out (dead before any output is written)
#define AGG_OFF  0L
#define ET_OFF   51200000L
#define WT0_OFF  51225600L
#define WT1_OFF  51258368L
#define WT2_OFF  51291136L
#define BPQ_OFF  51323904L
#define LB_OFF   51352576L
#define B1_OFF   51353088L
#define B2_OFF   51353600L

__device__ __forceinline__ float b2f(bf16 v) { return __bfloat162float(v); }
__device__ __forceinline__ float bits2f(unsigned short s) {
    unsigned u = ((unsigned)s) << 16; float f; __builtin_memcpy(&f, &u, 4); return f;
}
__device__ __forceinline__ unsigned short f2bits(float f) {
    bf16 h = __float2bfloat16(f); unsigned short s; __builtin_memcpy(&s, &h, 2); return s;
}
__device__ __forceinline__ float ldf(const void* p, size_t i, int isbf) {
    return isbf ? __bfloat162float(((const bf16*)p)[i]) : ((const float*)p)[i];
}
__device__ __forceinline__ void stout(void* p, size_t i, int isbf, float v) {
    if (isbf) ((bf16*)p)[i] = __float2bfloat16(v);
    else      ((float*)p)[i] = v;
}

// ---- dtype probe ----
__global__ void probe_kernel(const void* __restrict__ table, int* __restrict__ flag) {
    __shared__ int bad[256];
    int t = threadIdx.x;
    const bf16* p = (const bf16*)table;
    int cnt = 0;
    for (int i = 0; i < 64; i++) {
        float v = __bfloat162float(p[t * 64 + i]);
        if (!isfinite(v) || fabsf(v) > 1000.0f) cnt++;
    }
    bad[t] = cnt;
    __syncthreads();
    for (int s = 128; s > 0; s >>= 1) {
        if (t < s) bad[t] += bad[t + s];
        __syncthreads();
    }
    if (t == 0) *flag = (bad[0] == 0) ? 1 : 0;   // 1 = bf16, 0 = fp32
}

// ---- prepack: WT[n][k] = W[k][n] (bf16), BPQ[j][k] from edge_W, biases fp32 ----
__global__ void prepack_kernel(const int* __restrict__ flag,
                               const void* __restrict__ linW, const void* __restrict__ w1,
                               const void* __restrict__ w2, const void* __restrict__ edgeW,
                               const void* __restrict__ linb, const void* __restrict__ bb1,
                               const void* __restrict__ bb2,
                               unsigned short* __restrict__ WT0, unsigned short* __restrict__ WT1,
                               unsigned short* __restrict__ WT2, unsigned short* __restrict__ BPQ,
                               float* __restrict__ LB, float* __restrict__ B1p, float* __restrict__ B2p) {
    int isbf = *flag;
    int g = blockIdx.x * 256 + threadIdx.x;
    if (g < 3 * 16384) {
        int w = g / 16384, i = g % 16384;
        int n = i >> 7, k = i & 127;
        const void* src = (w == 0) ? linW : (w == 1) ? w1 : w2;
        unsigned short* dst = (w == 0) ? WT0 : (w == 1) ? WT1 : WT2;
        dst[i] = f2bits(ldf(src, (size_t)k * 128 + n, isbf));
    } else if (g < 3 * 16384 + 112 * 128) {
        int i = g - 3 * 16384;
        int j = i >> 7, k = i & 127;
        float v = 0.0f;
        if (j < 50)       v = ldf(edgeW, (size_t)k * 50 + j, isbf);
        else if (j < 100) v = ldf(edgeW, (size_t)(128 + k) * 50 + (j - 50), isbf);
        BPQ[i] = f2bits(v);
    } else if (g < 3 * 16384 + 112 * 128 + 3 * 128) {
        int i = g - (3 * 16384 + 112 * 128);
        int w = i >> 7, n = i & 127;
        const void* src = (w == 0) ? linb : (w == 1) ? bb1 : bb2;
        float* dst = (w == 0) ? LB : (w == 1) ? B1p : B2p;
        dst[n] = ldf(src, n, isbf);
    }
}

// ---- ET (50 rows only): relu(l2norm(rel_emb) @ lin_W + lin_b) fp32 ----
__global__ void et_kernel(const int* __restrict__ flag,
                          const void* __restrict__ table,
                          const void* __restrict__ W,
                          const void* __restrict__ bias,
                          float* __restrict__ out) {
    int isbf = *flag;
    int row = blockIdx.x;
    int t = threadIdx.x;
    float v = ldf(table, (size_t)row * D_C + t, isbf);
    __shared__ float sv[D_C];
    __shared__ float red[D_C];
    red[t] = v * v;
    __syncthreads();
    for (int s = 64; s > 0; s >>= 1) {
        if (t < s) red[t] += red[t + s];
        __syncthreads();
    }
    float nrm = fmaxf(sqrtf(red[0]), 1e-12f);
    sv[t] = v / nrm;
    __syncthreads();
    float acc = ldf(bias, t, isbf);
    for (int k = 0; k < D_C; k++) acc = fmaf(sv[k], ldf(W, k * D_C + t, isbf), acc);
    out[(size_t)row * D_C + t] = fmaxf(acc, 0.0f);
}

// ---- normalize: one wave per row, 2 elems/lane ----
__global__ void normalize_kernel(const int* __restrict__ flag,
                                 const int* __restrict__ ids,
                                 const void* __restrict__ table,
                                 unsigned short* __restrict__ out) {
    int w = (int)((blockIdx.x * (long)blockDim.x + threadIdx.x) >> 6);
    int lane = threadIdx.x & 63;
    if (w >= N_NODES_C) return;
    int isbf = *flag;
    int id = ids[w];
    float v0, v1;
    if (isbf) {
        const unsigned short* p = (const unsigned short*)table + (size_t)id * D_C + lane * 2;
        ushort2 u = *(const ushort2*)p;
        v0 = bits2f(u.x); v1 = bits2f(u.y);
    } else {
        const float* p = (const float*)table + (size_t)id * D_C + lane * 2;
        float2 f = *(const float2*)p;
        v0 = f.x; v1 = f.y;
    }
    float ss = v0 * v0 + v1 * v1;
#pragma unroll
    for (int o = 32; o > 0; o >>= 1) ss += __shfl_down(ss, o, 64);
    ss = __shfl(ss, 0, 64);
    float inv = 1.0f / fmaxf(sqrtf(ss), 1e-12f);
    ushort2 o2;
    o2.x = f2bits(v0 * inv);
    o2.y = f2bits(v1 * inv);
    *(ushort2*)(out + (size_t)w * D_C + lane * 2) = o2;
}

// ---- MFMA GEMM: Y[M,NOUT] = act((X[+AGG]) @ BT^T + bias), K=128 resident ----
template <int NOUT, bool RELU, bool ADD_AGG, bool HAS_BIAS>
__global__ __launch_bounds__(256, 2) void gemm_kernel(
        const unsigned short* __restrict__ X,   // [M,128] bf16 bits
        const float* __restrict__ AGG,          // [M,128] fp32 (or null)
        const unsigned short* __restrict__ BT,  // [NT*16,128] bf16 bits, row n holds W[:,n]
        const float* __restrict__ bias,         // [NOUT] fp32 (or null)
        unsigned short* __restrict__ Y,         // [M,NOUT] bf16 bits
        int M) {
    constexpr int NT = (NOUT + 15) / 16;
    __shared__ short Als[128 * 128];
    __shared__ short Bls[NT * 16 * 128];
    int t = threadIdx.x;
    int m0 = blockIdx.x * 128;

    // stage A (optionally + AGG)
#pragma unroll
    for (int p = 0; p < 8; p++) {
        int lin = (p * 256 + t) * 8;
        int row = lin >> 7, col = lin & 127;
        int gr = m0 + row; if (gr >= M) gr = M - 1;
        short8 xv = *(const short8*)(X + (size_t)gr * 128 + col);
        if (ADD_AGG) {
            const float* ap = AGG + (size_t)gr * 128 + col;
            float4v a0 = *(const float4v*)ap;
            float4v a1 = *(const float4v*)(ap + 4);
            short8 r;
#pragma unroll
            for (int i = 0; i < 4; i++) r[i] = (short)f2bits(bits2f((unsigned short)xv[i]) + a0[i]);
#pragma unroll
            for (int i = 0; i < 4; i++) r[4 + i] = (short)f2bits(bits2f((unsigned short)xv[4 + i]) + a1[i]);
            xv = r;
        }
        *(short8*)&Als[lin] = xv;
    }
    // stage B
    constexpr int BELEMS = NT * 16 * 128;
#pragma unroll
    for (int p = 0; p * 2048 < BELEMS; p++) {
        int lin = (p * 256 + t) * 8;
        if (lin < BELEMS) *(short8*)&Bls[lin] = *(const short8*)(BT + lin);
    }
    __syncthreads();

    int wave = t >> 6, lane = t & 63;
    int quad = lane >> 4, lr = lane & 15;
    int wr0 = wave * 32;

    short8 afr[2][4];
#pragma unroll
    for (int mt = 0; mt < 2; mt++)
#pragma unroll
        for (int kk = 0; kk < 4; kk++)
            afr[mt][kk] = *(short8*)&Als[(wr0 + mt * 16 + lr) * 128 + kk * 32 + quad * 8];

#pragma unroll
    for (int nt = 0; nt < NT; nt++) {
        short8 bfr[4];
#pragma unroll
        for (int kk = 0; kk < 4; kk++)
            bfr[kk] = *(short8*)&Bls[(nt * 16 + lr) * 128 + kk * 32 + quad * 8];
        int col = nt * 16 + lr;
        float bs = 0.0f;
        if (HAS_BIAS) bs = bias[col];
#pragma unroll
        for (int mt = 0; mt < 2; mt++) {
            float4v acc = {0.0f, 0.0f, 0.0f, 0.0f};
#pragma unroll
            for (int kk = 0; kk < 4; kk++)
                acc = __builtin_amdgcn_mfma_f32_16x16x32_bf16(afr[mt][kk], bfr[kk], acc, 0, 0, 0);
            int rbase = m0 + wr0 + mt * 16 + quad * 4;
#pragma unroll
            for (int r = 0; r < 4; r++) {
                int row = rbase + r;
                float v = acc[r] + bs;
                if (RELU) v = fmaxf(v, 0.0f);
                if (row < M && ((NOUT & 15) == 0 || col < NOUT))
                    Y[(size_t)row * NOUT + col] = f2bits(v);
            }
        }
    }
}

// ---- scatter: agg[dst] += relu(x[src] + etab[rel]) ----
__global__ void scatter_kernel(const bf16* __restrict__ x,
                               const int* __restrict__ ei,
                               const int* __restrict__ rel,
                               const float* __restrict__ etab,
                               float* __restrict__ agg) {
    long idx = (long)blockIdx.x * blockDim.x + threadIdx.x;
    if (idx >= (long)N_EDGES_C * D_C) return;
    int e = (int)(idx >> 7);
    int t = (int)(idx & (D_C - 1));
    int src = ei[e];
    int dst = ei[N_EDGES_C + e];
    int r = rel[e];
    float m = b2f(x[(size_t)src * D_C + t]) + etab[r * D_C + t];
    m = fmaxf(m, 0.0f);
    atomicAdd(&agg[(size_t)dst * D_C + t], m);
}

// ---- edge head: out[e*50+j] = PQ[src][j] + PQ[dst][50+j] + eb[j] ----
__global__ void edge_out_kernel(const int* __restrict__ flag,
                                const int* __restrict__ ei,
                                const unsigned short* __restrict__ PQ,
                                const void* __restrict__ eb,
                                void* __restrict__ out) {
    int isbf = *flag;
    long g = (long)blockIdx.x * blockDim.x + threadIdx.x;
    if (g >= (long)N_EDGES_C * N_REL_C) return;
    int e = (int)(g / N_REL_C);
    int j = (int)(g - (long)e * N_REL_C);
    int src = ei[e];
    int dst = ei[N_EDGES_C + e];
    float v = bits2f(PQ[(size_t)src * 100 + j]) + bits2f(PQ[(size_t)dst * 100 + 50 + j]) + ldf(eb, j, isbf);
    stout(out, EO_EDGE + g, isbf, v);
}

__global__ void motif_kernel(const int* __restrict__ flag,
                             const int* __restrict__ cidx,
                             const bf16* __restrict__ x,
                             const void* __restrict__ W,
                             const void* __restrict__ bias,
                             void* __restrict__ out) {
    int isbf = *flag;
    int row = blockIdx.x;
    int t = threadIdx.x;
    __shared__ float sv[D_C];
    int id = cidx[row];
    sv[t] = b2f(x[(size_t)id * D_C + t]);
    __syncthreads();
    if (t < N_MOTIF_C) {
        float acc = ldf(bias, t, isbf);
        for (int k = 0; k < D_C; k++) acc = fmaf(sv[k], ldf(W, k * N_MOTIF_C + t, isbf), acc);
        stout(out, EO_MOTIF + (size_t)row * N_MOTIF_C + t, isbf, acc);
    }
}

__global__ void nodec_kernel(const int* __restrict__ flag,
                             const int* __restrict__ nidx,
                             const bf16* __restrict__ x,
                             const void* __restrict__ W,
                             const void* __restrict__ bias,
                             void* __restrict__ out) {
    int isbf = *flag;
    int g = blockIdx.x * blockDim.x + threadIdx.x;
    if (g >= N_NONMOL_C * 15) return;
    int row = g / 15;
    int j = g - row * 15;
    int id = nidx[row];
    float acc = ldf(bias, j, isbf);
    for (int k = 0; k < D_C; k++) acc = fmaf(b2f(x[(size_t)id * D_C + k]), ldf(W, k * 15 + j, isbf), acc);
    stout(out, EO_NODEC + g, isbf, acc);
}

__global__ void binary_kernel(const int* __restrict__ flag,
                              const bf16* __restrict__ x,
                              const void* __restrict__ W,
                              const void* __restrict__ bias,
                              void* __restrict__ out) {
    int isbf = *flag;
    int g = blockIdx.x * blockDim.x + threadIdx.x;
    int row = g >> 6;
    int lane = threadIdx.x & 63;
    if (row >= N_NODES_C) return;
    float a = b2f(x[(size_t)row * D_C + lane]) * ldf(W, lane, isbf) +
              b2f(x[(size_t)row * D_C + 64 + lane]) * ldf(W, 64 + lane, isbf);
#pragma unroll
    for (int off = 32; off > 0; off >>= 1) a += __shfl_down(a, off, 64);
    if (lane == 0) stout(out, EO_BIN + row, isbf, a + ldf(bias, 0, isbf));
}

extern "C" void kernel_launch(void* const* d_in, const int* in_sizes, int n_in,
                              void* d_out, int out_size, void* d_ws, size_t ws_size,
                              hipStream_t stream) {
    const int* node_ids = (const int*)d_in[0];
    const int* rel_ids  = (const int*)d_in[1];
    const int* center   = (const int*)d_in[2];
    const int* nonmol   = (const int*)d_in[3];
    const int* ei       = (const int*)d_in[4];
    const void* node_emb = d_in[5];
    const void* rel_emb  = d_in[6];
    const void* lin_W = d_in[7];
    const void* lin_b = d_in[8];
    const void* W1 = d_in[9];
    const void* b1 = d_in[10];
    const void* W2 = d_in[11];
    const void* b2 = d_in[12];
    const void* edge_W = d_in[13];
    const void* edge_b = d_in[14];
    const void* motif_W = d_in[15];
    const void* motif_b = d_in[16];
    const void* nodec_W = d_in[17];
    const void* nodec_b = d_in[18];
    const void* bin_W = d_in[19];
    const void* bin_b = d_in[20];

    // ws: X0 [0,25.6MB), X1 [25.6,51.2MB), FLAG (4B)
    char* wsb = (char*)d_ws;
    unsigned short* X0 = (unsigned short*)wsb;                               // x0 -> x2 (in-place reuse)
    unsigned short* X1 = (unsigned short*)(wsb + (size_t)N_NODES_C * D_C * 2); // x1 -> PQ
    int* FLAG = (int*)(wsb + (size_t)2 * N_NODES_C * D_C * 2);
    unsigned short* PQ = X1;

    // scratch carved from dead d_out space
    char* ob = (char*)d_out;
    float* AGG = (float*)(ob + AGG_OFF);
    float* ET  = (float*)(ob + ET_OFF);
    unsigned short* WT0 = (unsigned short*)(ob + WT0_OFF);
    unsigned short* WT1 = (unsigned short*)(ob + WT1_OFF);
    unsigned short* WT2 = (unsigned short*)(ob + WT2_OFF);
    unsigned short* BPQ = (unsigned short*)(ob + BPQ_OFF);
    float* LB  = (float*)(ob + LB_OFF);
    float* B1p = (float*)(ob + B1_OFF);
    float* B2p = (float*)(ob + B2_OFF);

    const size_t agg_bytes = (size_t)N_NODES_C * D_C * sizeof(float);
    const int gemm_blocks = (N_NODES_C + 127) / 128;   // 782

    probe_kernel<<<1, 256, 0, stream>>>(node_emb, FLAG);
    prepack_kernel<<<250, 256, 0, stream>>>(FLAG, lin_W, W1, W2, edge_W, lin_b, b1, b2,
                                            WT0, WT1, WT2, BPQ, LB, B1p, B2p);
    et_kernel<<<N_REL_C, D_C, 0, stream>>>(FLAG, rel_emb, lin_W, lin_b, ET);

    // X0 = l2norm(node_emb[node_ids]) (bf16), then in-place X0 = relu(X0 @ lin_W + lin_b)
    normalize_kernel<<<(N_NODES_C * 64 + 255) / 256, 256, 0, stream>>>(FLAG, node_ids, node_emb, X0);
    gemm_kernel<128, true, false, true><<<gemm_blocks, 256, 0, stream>>>(X0, nullptr, WT0, LB, X0, N_NODES_C);

    // GINE conv 1: X1 = relu((X0 + AGG) @ W1 + b1)
    hipMemsetAsync(AGG, 0, agg_bytes, stream);
    scatter_kernel<<<(int)(((long)N_EDGES_C * D_C + 255) / 256), 256, 0, stream>>>(
        (const bf16*)X0, ei, rel_ids, ET, AGG);
    gemm_kernel<128, true, true, true><<<gemm_blocks, 256, 0, stream>>>(X0, AGG, WT1, B1p, X1, N_NODES_C);

    // GINE conv 2: X2(=X0 slot) = (X1 + AGG) @ W2 + b2
    hipMemsetAsync(AGG, 0, agg_bytes, stream);
    scatter_kernel<<<(int)(((long)N_EDGES_C * D_C + 255) / 256), 256, 0, stream>>>(
        (const bf16*)X1, ei, rel_ids, ET, AGG);
    gemm_kernel<128, false, true, true><<<gemm_blocks, 256, 0, stream>>>(X1, AGG, WT2, B2p, X0, N_NODES_C);

    // PQ = X2 @ [edge_W halves]  -> [N,100] (P cols 0..49, Q cols 50..99)
    gemm_kernel<100, false, false, false><<<gemm_blocks, 256, 0, stream>>>(X0, nullptr, BPQ, nullptr, PQ, N_NODES_C);

    long ethreads = (long)N_EDGES_C * N_REL_C;
    edge_out_kernel<<<(int)((ethreads + 255) / 256), 256, 0, stream>>>(FLAG, ei, PQ, edge_b, d_out);

    motif_kernel<<<N_CENTER_C, D_C, 0, stream>>>(FLAG, center, (const bf16*)X0, motif_W, motif_b, d_out);
    nodec_kernel<<<(N_NONMOL_C * 15 + 255) / 256, 256, 0, stream>>>(FLAG, nonmol, (const bf16*)X0, nodec_W, nodec_b, d_out);
    binary_kernel<<<(N_NODES_C * 64 + 255) / 256, 256, 0, stream>>>(FLAG, (const bf16*)X0, bin_W, bin_b, d_out);
}

// Round 6
// 840.791 us; speedup vs baseline: 1.9749x; 1.2519x over previous
//
#include <hip/hip_runtime.h>
#include <hip/hip_bf16.h>
#include <math.h>

typedef __hip_bfloat16 bf16;
typedef __attribute__((ext_vector_type(8))) short short8;
typedef __attribute__((ext_vector_type(4))) float float4v;

#define N_NODES_C 100000
#define N_EDGES_C 600000
#define N_CENTER_C 512
#define N_NONMOL_C 20000
#define N_REL_C 50
#define D_C 128
#define N_MOTIF_C 85

// element offsets into d_out (dtype-independent)
#define EO_EDGE  0L
#define EO_MOTIF 30000000L
#define EO_NODEC 30043520L
#define EO_BIN   30343520L

// byte offsets of scratch inside d_out (dead before any output is written;
// edge_out (first writer of d_out[0..60MB)) runs after all scratch consumers)
#define AGG_OFF  0L
#define ET_OFF   51200000L
#define WT0_OFF  51225600L
#define WT1_OFF  51258368L
#define WT2_OFF  51291136L
#define BPQ_OFF  51323904L
#define LB_OFF   51352576L
#define B1_OFF   51353088L
#define B2_OFF   51353600L
#define OFFS_OFF 51354112L
#define BSUM_OFF 51755680L
#define SSRC_OFF 51757248L
#define SREL_OFF 54157248L
// ends 56,557,248 < 60,887,040 (min d_out size, bf16 case)

__device__ __forceinline__ float b2f(bf16 v) { return __bfloat162float(v); }
__device__ __forceinline__ float bits2f(unsigned short s) {
    unsigned u = ((unsigned)s) << 16; float f; __builtin_memcpy(&f, &u, 4); return f;
}
__device__ __forceinline__ unsigned short f2bits(float f) {
    bf16 h = __float2bfloat16(f); unsigned short s; __builtin_memcpy(&s, &h, 2); return s;
}
__device__ __forceinline__ float ldf(const void* p, size_t i, int isbf) {
    return isbf ? __bfloat162float(((const bf16*)p)[i]) : ((const float*)p)[i];
}
__device__ __forceinline__ void stout(void* p, size_t i, int isbf, float v) {
    if (isbf) ((bf16*)p)[i] = __float2bfloat16(v);
    else      ((float*)p)[i] = v;
}

// ---- dtype probe ----
__global__ void probe_kernel(const void* __restrict__ table, int* __restrict__ flag) {
    __shared__ int bad[256];
    int t = threadIdx.x;
    const bf16* p = (const bf16*)table;
    int cnt = 0;
    for (int i = 0; i < 64; i++) {
        float v = __bfloat162float(p[t * 64 + i]);
        if (!isfinite(v) || fabsf(v) > 1000.0f) cnt++;
    }
    bad[t] = cnt;
    __syncthreads();
    for (int s = 128; s > 0; s >>= 1) {
        if (t < s) bad[t] += bad[t + s];
        __syncthreads();
    }
    if (t == 0) *flag = (bad[0] == 0) ? 1 : 0;   // 1 = bf16, 0 = fp32
}

// ---- prepack: WT[n][k] = W[k][n] (bf16), BPQ[j][k] from edge_W, biases fp32 ----
__global__ void prepack_kernel(const int* __restrict__ flag,
                               const void* __restrict__ linW, const void* __restrict__ w1,
                               const void* __restrict__ w2, const void* __restrict__ edgeW,
                               const void* __restrict__ linb, const void* __restrict__ bb1,
                               const void* __restrict__ bb2,
                               unsigned short* __restrict__ WT0, unsigned short* __restrict__ WT1,
                               unsigned short* __restrict__ WT2, unsigned short* __restrict__ BPQ,
                               float* __restrict__ LB, float* __restrict__ B1p, float* __restrict__ B2p) {
    int isbf = *flag;
    int g = blockIdx.x * 256 + threadIdx.x;
    if (g < 3 * 16384) {
        int w = g / 16384, i = g % 16384;
        int n = i >> 7, k = i & 127;
        const void* src = (w == 0) ? linW : (w == 1) ? w1 : w2;
        unsigned short* dst = (w == 0) ? WT0 : (w == 1) ? WT1 : WT2;
        dst[i] = f2bits(ldf(src, (size_t)k * 128 + n, isbf));
    } else if (g < 3 * 16384 + 112 * 128) {
        int i = g - 3 * 16384;
        int j = i >> 7, k = i & 127;
        float v = 0.0f;
        if (j < 50)       v = ldf(edgeW, (size_t)k * 50 + j, isbf);
        else if (j < 100) v = ldf(edgeW, (size_t)(128 + k) * 50 + (j - 50), isbf);
        BPQ[i] = f2bits(v);
    } else if (g < 3 * 16384 + 112 * 128 + 3 * 128) {
        int i = g - (3 * 16384 + 112 * 128);
        int w = i >> 7, n = i & 127;
        const void* src = (w == 0) ? linb : (w == 1) ? bb1 : bb2;
        float* dst = (w == 0) ? LB : (w == 1) ? B1p : B2p;
        dst[n] = ldf(src, n, isbf);
    }
}

// ---- ET (50 rows only): relu(l2norm(rel_emb) @ lin_W + lin_b) fp32 ----
__global__ void et_kernel(const int* __restrict__ flag,
                          const void* __restrict__ table,
                          const void* __restrict__ W,
                          const void* __restrict__ bias,
                          float* __restrict__ out) {
    int isbf = *flag;
    int row = blockIdx.x;
    int t = threadIdx.x;
    float v = ldf(table, (size_t)row * D_C + t, isbf);
    __shared__ float sv[D_C];
    __shared__ float red[D_C];
    red[t] = v * v;
    __syncthreads();
    for (int s = 64; s > 0; s >>= 1) {
        if (t < s) red[t] += red[t + s];
        __syncthreads();
    }
    float nrm = fmaxf(sqrtf(red[0]), 1e-12f);
    sv[t] = v / nrm;
    __syncthreads();
    float acc = ldf(bias, t, isbf);
    for (int k = 0; k < D_C; k++) acc = fmaf(sv[k], ldf(W, k * D_C + t, isbf), acc);
    out[(size_t)row * D_C + t] = fmaxf(acc, 0.0f);
}

// ---- normalize: one wave per row, 2 elems/lane ----
__global__ void normalize_kernel(const int* __restrict__ flag,
                                 const int* __restrict__ ids,
                                 const void* __restrict__ table,
                                 unsigned short* __restrict__ out) {
    int w = (int)((blockIdx.x * (long)blockDim.x + threadIdx.x) >> 6);
    int lane = threadIdx.x & 63;
    if (w >= N_NODES_C) return;
    int isbf = *flag;
    int id = ids[w];
    float v0, v1;
    if (isbf) {
        const unsigned short* p = (const unsigned short*)table + (size_t)id * D_C + lane * 2;
        ushort2 u = *(const ushort2*)p;
        v0 = bits2f(u.x); v1 = bits2f(u.y);
    } else {
        const float* p = (const float*)table + (size_t)id * D_C + lane * 2;
        float2 f = *(const float2*)p;
        v0 = f.x; v1 = f.y;
    }
    float ss = v0 * v0 + v1 * v1;
#pragma unroll
    for (int o = 32; o > 0; o >>= 1) ss += __shfl_down(ss, o, 64);
    ss = __shfl(ss, 0, 64);
    float inv = 1.0f / fmaxf(sqrtf(ss), 1e-12f);
    ushort2 o2;
    o2.x = f2bits(v0 * inv);
    o2.y = f2bits(v1 * inv);
    *(ushort2*)(out + (size_t)w * D_C + lane * 2) = o2;
}

// ---- MFMA GEMM: Y[M,NOUT] = act((X[+AGG]) @ BT^T + bias), K=128 resident ----
template <int NOUT, bool RELU, bool ADD_AGG, bool HAS_BIAS>
__global__ __launch_bounds__(256, 2) void gemm_kernel(
        const unsigned short* __restrict__ X,   // [M,128] bf16 bits
        const float* __restrict__ AGG,          // [M,128] fp32 (or null)
        const unsigned short* __restrict__ BT,  // [NT*16,128] bf16 bits, row n holds W[:,n]
        const float* __restrict__ bias,         // [NOUT] fp32 (or null)
        unsigned short* __restrict__ Y,         // [M,NOUT] bf16 bits
        int M) {
    constexpr int NT = (NOUT + 15) / 16;
    __shared__ short Als[128 * 128];
    __shared__ short Bls[NT * 16 * 128];
    int t = threadIdx.x;
    int m0 = blockIdx.x * 128;

#pragma unroll
    for (int p = 0; p < 8; p++) {
        int lin = (p * 256 + t) * 8;
        int row = lin >> 7, col = lin & 127;
        int gr = m0 + row; if (gr >= M) gr = M - 1;
        short8 xv = *(const short8*)(X + (size_t)gr * 128 + col);
        if (ADD_AGG) {
            const float* ap = AGG + (size_t)gr * 128 + col;
            float4v a0 = *(const float4v*)ap;
            float4v a1 = *(const float4v*)(ap + 4);
            short8 r;
#pragma unroll
            for (int i = 0; i < 4; i++) r[i] = (short)f2bits(bits2f((unsigned short)xv[i]) + a0[i]);
#pragma unroll
            for (int i = 0; i < 4; i++) r[4 + i] = (short)f2bits(bits2f((unsigned short)xv[4 + i]) + a1[i]);
            xv = r;
        }
        *(short8*)&Als[lin] = xv;
    }
    constexpr int BELEMS = NT * 16 * 128;
#pragma unroll
    for (int p = 0; p * 2048 < BELEMS; p++) {
        int lin = (p * 256 + t) * 8;
        if (lin < BELEMS) *(short8*)&Bls[lin] = *(const short8*)(BT + lin);
    }
    __syncthreads();

    int wave = t >> 6, lane = t & 63;
    int quad = lane >> 4, lr = lane & 15;
    int wr0 = wave * 32;

    short8 afr[2][4];
#pragma unroll
    for (int mt = 0; mt < 2; mt++)
#pragma unroll
        for (int kk = 0; kk < 4; kk++)
            afr[mt][kk] = *(short8*)&Als[(wr0 + mt * 16 + lr) * 128 + kk * 32 + quad * 8];

#pragma unroll
    for (int nt = 0; nt < NT; nt++) {
        short8 bfr[4];
#pragma unroll
        for (int kk = 0; kk < 4; kk++)
            bfr[kk] = *(short8*)&Bls[(nt * 16 + lr) * 128 + kk * 32 + quad * 8];
        int col = nt * 16 + lr;
        float bs = 0.0f;
        if (HAS_BIAS) bs = bias[col];
#pragma unroll
        for (int mt = 0; mt < 2; mt++) {
            float4v acc = {0.0f, 0.0f, 0.0f, 0.0f};
#pragma unroll
            for (int kk = 0; kk < 4; kk++)
                acc = __builtin_amdgcn_mfma_f32_16x16x32_bf16(afr[mt][kk], bfr[kk], acc, 0, 0, 0);
            int rbase = m0 + wr0 + mt * 16 + quad * 4;
#pragma unroll
            for (int r = 0; r < 4; r++) {
                int row = rbase + r;
                float v = acc[r] + bs;
                if (RELU) v = fmaxf(v, 0.0f);
                if (row < M && ((NOUT & 15) == 0 || col < NOUT))
                    Y[(size_t)row * NOUT + col] = f2bits(v);
            }
        }
    }
}

// ================= counting sort of edges by dst =================
__global__ void hist_kernel(const int* __restrict__ ei, int* __restrict__ cnt) {
    int e = blockIdx.x * 256 + threadIdx.x;
    if (e < N_EDGES_C) atomicAdd(&cnt[ei[N_EDGES_C + e]], 1);
}

// in-place: cnt -> exclusive-scan-within-block; bsum[b] = block total
__global__ void scan1_kernel(int* __restrict__ cnt, int* __restrict__ bsum) {
    __shared__ int s[256];
    int t = threadIdx.x;
    int idx = blockIdx.x * 256 + t;
    int v = (idx < N_NODES_C) ? cnt[idx] : 0;
    s[t] = v;
    __syncthreads();
    for (int o = 1; o < 256; o <<= 1) {
        int u = (t >= o) ? s[t - o] : 0;
        __syncthreads();
        s[t] += u;
        __syncthreads();
    }
    if (idx < N_NODES_C) cnt[idx] = s[t] - v;     // exclusive within block
    if (t == 255) bsum[blockIdx.x] = s[255];      // block total
}

// single block: bsum -> exclusive scan (NB=391 <= 512)
__global__ void scan2_kernel(int* __restrict__ bsum, int nb) {
    __shared__ int s[512];
    int t = threadIdx.x;
    int v = (t < nb) ? bsum[t] : 0;
    s[t] = v;
    __syncthreads();
    for (int o = 1; o < 512; o <<= 1) {
        int u = (t >= o) ? s[t - o] : 0;
        __syncthreads();
        s[t] += u;
        __syncthreads();
    }
    if (t < nb) bsum[t] = s[t] - v;               // exclusive
}

__global__ void scan3_kernel(int* __restrict__ cnt, const int* __restrict__ bsum) {
    int idx = blockIdx.x * 256 + threadIdx.x;
    if (idx < N_NODES_C) cnt[idx] += bsum[blockIdx.x];
}

// place edges; after this, offs[n] = end of segment n (start = offs[n-1], offs[-1]=0)
__global__ void sort_scatter_kernel(const int* __restrict__ ei, const int* __restrict__ rel,
                                    int* __restrict__ offs,
                                    int* __restrict__ ssrc, int* __restrict__ srel) {
    int e = blockIdx.x * 256 + threadIdx.x;
    if (e >= N_EDGES_C) return;
    int dst = ei[N_EDGES_C + e];
    int pos = atomicAdd(&offs[dst], 1);
    ssrc[pos] = ei[e];
    srel[pos] = rel[e];
}

// agg[n][t] = sum over n's in-edges of relu(x[src]+ET[rel]); no atomics
__global__ __launch_bounds__(256) void gather_agg_kernel(
        const unsigned short* __restrict__ x,
        const int* __restrict__ offs,
        const int* __restrict__ ssrc, const int* __restrict__ srel,
        const float* __restrict__ etab,
        float* __restrict__ agg) {
    int t = threadIdx.x;
    int node = blockIdx.x * 2 + (t >> 7);
    int feat = t & 127;
    if (node >= N_NODES_C) return;
    int start = (node == 0) ? 0 : offs[node - 1];
    int end = offs[node];
    float acc = 0.0f;
    for (int e = start; e < end; e++) {
        int src = ssrc[e];
        int r = srel[e];
        acc += fmaxf(bits2f(x[(size_t)src * D_C + feat]) + etab[r * D_C + feat], 0.0f);
    }
    agg[(size_t)node * D_C + feat] = acc;
}

// ---- edge head: out[e*50+j] = PQ[src][j] + PQ[dst][50+j] + eb[j] ----
__global__ void edge_out_kernel(const int* __restrict__ flag,
                                const int* __restrict__ ei,
                                const unsigned short* __restrict__ PQ,
                                const void* __restrict__ eb,
                                void* __restrict__ out) {
    int isbf = *flag;
    long g = (long)blockIdx.x * blockDim.x + threadIdx.x;
    if (g >= (long)N_EDGES_C * N_REL_C) return;
    int e = (int)(g / N_REL_C);
    int j = (int)(g - (long)e * N_REL_C);
    int src = ei[e];
    int dst = ei[N_EDGES_C + e];
    float v = bits2f(PQ[(size_t)src * 100 + j]) + bits2f(PQ[(size_t)dst * 100 + 50 + j]) + ldf(eb, j, isbf);
    stout(out, EO_EDGE + g, isbf, v);
}

__global__ void motif_kernel(const int* __restrict__ flag,
                             const int* __restrict__ cidx,
                             const bf16* __restrict__ x,
                             const void* __restrict__ W,
                             const void* __restrict__ bias,
                             void* __restrict__ out) {
    int isbf = *flag;
    int row = blockIdx.x;
    int t = threadIdx.x;
    __shared__ float sv[D_C];
    int id = cidx[row];
    sv[t] = b2f(x[(size_t)id * D_C + t]);
    __syncthreads();
    if (t < N_MOTIF_C) {
        float acc = ldf(bias, t, isbf);
        for (int k = 0; k < D_C; k++) acc = fmaf(sv[k], ldf(W, k * N_MOTIF_C + t, isbf), acc);
        stout(out, EO_MOTIF + (size_t)row * N_MOTIF_C + t, isbf, acc);
    }
}

__global__ void nodec_kernel(const int* __restrict__ flag,
                             const int* __restrict__ nidx,
                             const bf16* __restrict__ x,
                             const void* __restrict__ W,
                             const void* __restrict__ bias,
                             void* __restrict__ out) {
    int isbf = *flag;
    int g = blockIdx.x * blockDim.x + threadIdx.x;
    if (g >= N_NONMOL_C * 15) return;
    int row = g / 15;
    int j = g - row * 15;
    int id = nidx[row];
    float acc = ldf(bias, j, isbf);
    for (int k = 0; k < D_C; k++) acc = fmaf(b2f(x[(size_t)id * D_C + k]), ldf(W, k * 15 + j, isbf), acc);
    stout(out, EO_NODEC + g, isbf, acc);
}

__global__ void binary_kernel(const int* __restrict__ flag,
                              const bf16* __restrict__ x,
                              const void* __restrict__ W,
                              const void* __restrict__ bias,
                              void* __restrict__ out) {
    int isbf = *flag;
    int g = blockIdx.x * blockDim.x + threadIdx.x;
    int row = g >> 6;
    int lane = threadIdx.x & 63;
    if (row >= N_NODES_C) return;
    float a = b2f(x[(size_t)row * D_C + lane]) * ldf(W, lane, isbf) +
              b2f(x[(size_t)row * D_C + 64 + lane]) * ldf(W, 64 + lane, isbf);
#pragma unroll
    for (int off = 32; off > 0; off >>= 1) a += __shfl_down(a, off, 64);
    if (lane == 0) stout(out, EO_BIN + row, isbf, a + ldf(bias, 0, isbf));
}

extern "C" void kernel_launch(void* const* d_in, const int* in_sizes, int n_in,
                              void* d_out, int out_size, void* d_ws, size_t ws_size,
                              hipStream_t stream) {
    const int* node_ids = (const int*)d_in[0];
    const int* rel_ids  = (const int*)d_in[1];
    const int* center   = (const int*)d_in[2];
    const int* nonmol   = (const int*)d_in[3];
    const int* ei       = (const int*)d_in[4];
    const void* node_emb = d_in[5];
    const void* rel_emb  = d_in[6];
    const void* lin_W = d_in[7];
    const void* lin_b = d_in[8];
    const void* W1 = d_in[9];
    const void* b1 = d_in[10];
    const void* W2 = d_in[11];
    const void* b2 = d_in[12];
    const void* edge_W = d_in[13];
    const void* edge_b = d_in[14];
    const void* motif_W = d_in[15];
    const void* motif_b = d_in[16];
    const void* nodec_W = d_in[17];
    const void* nodec_b = d_in[18];
    const void* bin_W = d_in[19];
    const void* bin_b = d_in[20];

    // ws: X0 [0,25.6MB), X1 [25.6,51.2MB), FLAG (4B)
    char* wsb = (char*)d_ws;
    unsigned short* X0 = (unsigned short*)wsb;
    unsigned short* X1 = (unsigned short*)(wsb + (size_t)N_NODES_C * D_C * 2);
    int* FLAG = (int*)(wsb + (size_t)2 * N_NODES_C * D_C * 2);
    unsigned short* PQ = X1;

    // scratch carved from dead d_out space
    char* ob = (char*)d_out;
    float* AGG = (float*)(ob + AGG_OFF);
    float* ET  = (float*)(ob + ET_OFF);
    unsigned short* WT0 = (unsigned short*)(ob + WT0_OFF);
    unsigned short* WT1 = (unsigned short*)(ob + WT1_OFF);
    unsigned short* WT2 = (unsigned short*)(ob + WT2_OFF);
    unsigned short* BPQ = (unsigned short*)(ob + BPQ_OFF);
    float* LB  = (float*)(ob + LB_OFF);
    float* B1p = (float*)(ob + B1_OFF);
    float* B2p = (float*)(ob + B2_OFF);
    int* OFFS = (int*)(ob + OFFS_OFF);
    int* BSUM = (int*)(ob + BSUM_OFF);
    int* SSRC = (int*)(ob + SSRC_OFF);
    int* SREL = (int*)(ob + SREL_OFF);

    const int gemm_blocks = (N_NODES_C + 127) / 128;   // 782
    const int nscan = (N_NODES_C + 255) / 256;         // 391
    const int eblocks = (N_EDGES_C + 255) / 256;

    probe_kernel<<<1, 256, 0, stream>>>(node_emb, FLAG);
    prepack_kernel<<<250, 256, 0, stream>>>(FLAG, lin_W, W1, W2, edge_W, lin_b, b1, b2,
                                            WT0, WT1, WT2, BPQ, LB, B1p, B2p);
    et_kernel<<<N_REL_C, D_C, 0, stream>>>(FLAG, rel_emb, lin_W, lin_b, ET);

    // ---- counting sort of edges by dst (reused by both convs) ----
    hipMemsetAsync(OFFS, 0, N_NODES_C * sizeof(int), stream);
    hist_kernel<<<eblocks, 256, 0, stream>>>(ei, OFFS);
    scan1_kernel<<<nscan, 256, 0, stream>>>(OFFS, BSUM);
    scan2_kernel<<<1, 512, 0, stream>>>(BSUM, nscan);
    scan3_kernel<<<nscan, 256, 0, stream>>>(OFFS, BSUM);
    sort_scatter_kernel<<<eblocks, 256, 0, stream>>>(ei, rel_ids, OFFS, SSRC, SREL);

    // X0 = l2norm(node_emb[node_ids]), then in-place X0 = relu(X0 @ lin_W + lin_b)
    normalize_kernel<<<(N_NODES_C * 64 + 255) / 256, 256, 0, stream>>>(FLAG, node_ids, node_emb, X0);
    gemm_kernel<128, true, false, true><<<gemm_blocks, 256, 0, stream>>>(X0, nullptr, WT0, LB, X0, N_NODES_C);

    // GINE conv 1: X1 = relu((X0 + AGG) @ W1 + b1)
    gather_agg_kernel<<<(N_NODES_C + 1) / 2, 256, 0, stream>>>(X0, OFFS, SSRC, SREL, ET, AGG);
    gemm_kernel<128, true, true, true><<<gemm_blocks, 256, 0, stream>>>(X0, AGG, WT1, B1p, X1, N_NODES_C);

    // GINE conv 2: X2(=X0 slot) = (X1 + AGG) @ W2 + b2
    gather_agg_kernel<<<(N_NODES_C + 1) / 2, 256, 0, stream>>>(X1, OFFS, SSRC, SREL, ET, AGG);
    gemm_kernel<128, false, true, true><<<gemm_blocks, 256, 0, stream>>>(X1, AGG, WT2, B2p, X0, N_NODES_C);

    // PQ = X2 @ [edge_W halves]  -> [N,100]
    gemm_kernel<100, false, false, false><<<gemm_blocks, 256, 0, stream>>>(X0, nullptr, BPQ, nullptr, PQ, N_NODES_C);

    long ethreads = (long)N_EDGES_C * N_REL_C;
    edge_out_kernel<<<(int)((ethreads + 255) / 256), 256, 0, stream>>>(FLAG, ei, PQ, edge_b, d_out);

    motif_kernel<<<N_CENTER_C, D_C, 0, stream>>>(FLAG, center, (const bf16*)X0, motif_W, motif_b, d_out);
    nodec_kernel<<<(N_NONMOL_C * 15 + 255) / 256, 256, 0, stream>>>(FLAG, nonmol, (const bf16*)X0, nodec_W, nodec_b, d_out);
    binary_kernel<<<(N_NODES_C * 64 + 255) / 256, 256, 0, stream>>>(FLAG, (const bf16*)X0, bin_W, bin_b, d_out);
}